// Round 10
// baseline (1374.176 us; speedup 1.0000x reference)
//
#include <hip/hip_runtime.h>
#include <stdint.h>

#define NTHR 256
#define PP   28              // patches per block (252 conv1 tasks <= 256 threads)
#define PR   40              // patch row elems (27 used + pad)
#define PY   11              // rows incl. zero-pad rows y=0, y=10
#define PATCH_E (PY*PR)      // 440 elems per patch
#define HST  104             // H row stride in bf16 elems (K=96 + pad)
#define WST  104             // W2g row stride
#define NPATCH 32768
#define NCHUNK 11            // W2 window chunks per thread (128oc*22/256)

typedef __attribute__((ext_vector_type(8))) short bf16x8;
typedef __attribute__((ext_vector_type(4))) float f32x4;
typedef uint32_t u32;
typedef uint16_t u16;

__device__ __forceinline__ u16 f2bf(float f){
    u32 x = __float_as_uint(f);
    return (u16)((x + 0x7fffu + ((x >> 16) & 1u)) >> 16);
}
__device__ __forceinline__ void up2(u32 w, float& lo, float& hi){
    lo = __uint_as_float(w << 16);
    hi = __uint_as_float(w & 0xffff0000u);
}

__global__ __launch_bounds__(NTHR, 2)
void patch_embed(const float* __restrict__ images,
                 const float* __restrict__ coords,
                 const int*   __restrict__ t_src,
                 const float* __restrict__ W1,
                 const float* __restrict__ b1,
                 const float* __restrict__ W2,
                 const float* __restrict__ b2,
                 float* __restrict__ out)
{
    __shared__ __align__(16) u16 Pf[PP * PATCH_E];   // 24640 B (separate, NOT unioned)
    __shared__ __align__(16) u16 Hl[32 * HST];       //  6656 B (rows 28..31 stay zero)
    __shared__ __align__(16) u16 W2g[128 * WST];     // 26624 B
    __shared__ int poff[PP];                         // total ~58 KB -> 2 blk/CU

    const int tid  = threadIdx.x;
    const int blk  = blockIdx.x;
    const int lane = tid & 63;
    const int w    = tid >> 6;
    const int n16  = lane & 15;
    const int g4   = lane >> 4;
    const int HW   = 384 * 384;

    // per-patch source offsets (round-half-even like jnp.round)
    if (tid < PP) {
        int gp = blk * PP + tid;
        if (gp >= NPATCH) gp = NPATCH - 1;           // tail block: valid dummy
        int b = gp >> 11;
        int n = gp & 2047;
        float cx = coords[(size_t)(b * 2048 + n) * 2 + 0];
        float cy = coords[(size_t)(b * 2048 + n) * 2 + 1];
        int u = (int)rintf(cx * 384.0f);
        int v = (int)rintf(cy * 384.0f);
        u = min(max(u, 4), 379);
        v = min(max(v, 4), 379);
        int t = t_src[b * 2048 + n];
        t = min(max(t, 0), 15);
        poff[tid] = ((b * 16 + t) * 3) * HW + (v - 4) * 384 + (u - 4);
    }
    // zero Hl and W2g fully once (pads + unwritten rows stay zero forever)
    {
        u32* Hw  = (u32*)Hl;
        u32* Wgw = (u32*)W2g;
        for (int j = tid; j < 32 * (HST / 2); j += NTHR)  Hw[j]  = 0u;
        for (int j = tid; j < 128 * (WST / 2); j += NTHR) Wgw[j] = 0u;
    }
    __syncthreads();

    // stage patches: [p][y(11, zero-pad rows 0,10)][40 = 27 used + pad], bf16
    for (int i = tid; i < PP * PATCH_E; i += NTHR) {
        int p    = i / PATCH_E;
        int rem  = i - p * PATCH_E;
        int y    = rem / PR;
        int x40  = rem - y * PR;
        u16 v = 0;
        if (x40 < 27 && y >= 1 && y <= 9) {
            int c = x40 / 9;
            int x = x40 - c * 9;
            v = f2bf(images[(size_t)poff[p] + c * HW + (y - 1) * 384 + x]);
        }
        Pf[i] = v;
    }
    __syncthreads();

    // fixed conv1 task: (p0, y0); read 3x27 patch rows ONCE; unpack to fp32 regs
    const bool has = tid < PP * 9;                    // 252 tasks
    const int p0 = has ? tid / 9 : 0;
    const int y0 = has ? tid - 9 * (tid / 9) : 0;
    float rf[3][27];
    {
        const u16* tb = Pf + p0 * PATCH_E + y0 * PR;
        #pragma unroll
        for (int dy = 0; dy < 3; ++dy) {
            const u16* row = tb + dy * PR;
            uint4 q0 = *(const uint4*)(row);
            uint4 q1 = *(const uint4*)(row + 8);
            uint4 q2 = *(const uint4*)(row + 16);
            uint2 q3 = *(const uint2*)(row + 24);
            up2(q0.x, rf[dy][0],  rf[dy][1]);  up2(q0.y, rf[dy][2],  rf[dy][3]);
            up2(q0.z, rf[dy][4],  rf[dy][5]);  up2(q0.w, rf[dy][6],  rf[dy][7]);
            up2(q1.x, rf[dy][8],  rf[dy][9]);  up2(q1.y, rf[dy][10], rf[dy][11]);
            up2(q1.z, rf[dy][12], rf[dy][13]); up2(q1.w, rf[dy][14], rf[dy][15]);
            up2(q2.x, rf[dy][16], rf[dy][17]); up2(q2.y, rf[dy][18], rf[dy][19]);
            up2(q2.z, rf[dy][20], rf[dy][21]); up2(q2.w, rf[dy][22], rf[dy][23]);
            up2(q3.x, rf[dy][24], rf[dy][25]);
            rf[dy][26] = __uint_as_float(q3.y << 16);
        }
    }

    // W2 window prefetch for g=0 (round-8 pattern)
    const int oc_s = tid / 22;
    const int ch_s = tid - 22 * oc_s;
    uint4 wreg[NCHUNK];
    {
        int oc = oc_s, ch = ch_s;
        #pragma unroll
        for (int j = 0; j < NCHUNK; ++j) {
            int off = ch * 4;                          // base4(g=0) = 0
            off = off > 5180 ? 5180 : off;
            wreg[j] = *(const uint4*)(W2 + (size_t)oc * 5184 + off);
            oc += 11; ch += 14; if (ch >= 22) { ch -= 22; oc += 1; }   // flat += 256
        }
    }

    f32x4 acc[2][2];
    #pragma unroll
    for (int mt = 0; mt < 2; ++mt)
        #pragma unroll
        for (int nt = 0; nt < 2; ++nt) acc[mt][nt] = (f32x4){0.f, 0.f, 0.f, 0.f};

    for (int g = 0; g < 64; ++g) {
        // ---- conv1 for channel g: pure register FMAs ----
        const float* W1c = W1 + (size_t)g * 27;
        const float bias = b1[g];
        u16 h9[9];
        {
            float a[9];
            #pragma unroll
            for (int x = 0; x < 9; ++x) a[x] = bias;
            #pragma unroll
            for (int dy = 0; dy < 3; ++dy) {
                #pragma unroll
                for (int c = 0; c < 3; ++c) {
                    const float* rr = rf[dy] + c * 9;
                    const int wi = c * 9 + dy * 3;
                    const float w0 = W1c[wi], w1 = W1c[wi + 1], w2 = W1c[wi + 2];
                    #pragma unroll
                    for (int xo = 0; xo < 9; ++xo) {
                        a[xo] = fmaf(rr[xo], w1, a[xo]);
                        if (xo >= 1) a[xo] = fmaf(rr[xo - 1], w0, a[xo]);
                        if (xo <= 7) a[xo] = fmaf(rr[xo + 1], w2, a[xo]);
                    }
                }
            }
            #pragma unroll
            for (int xo = 0; xo < 9; ++xo) {
                float v = a[xo] > 0.f ? a[xo] : 0.f;   // ReLU
                h9[xo] = f2bf(v);
            }
        }

        __syncthreads();   // all waves done with MFMA(g-1) reads of Hl/W2g

        // H stores
        if (has) {
            #pragma unroll
            for (int xo = 0; xo < 9; ++xo) Hl[p0 * HST + y0 * 9 + xo] = h9[xo];
        }

        // commit prefetched W2 window (group g) -> W2g[oc][yx], guard yx in [0,81)
        {
            const int d = (g * 81) & 3;
            int oc = oc_s, ch = ch_s;
            #pragma unroll
            for (int j = 0; j < NCHUNK; ++j) {
                int yx0 = ch * 4 - d;
                float f0 = __uint_as_float(wreg[j].x);
                float f1 = __uint_as_float(wreg[j].y);
                float f2 = __uint_as_float(wreg[j].z);
                float f3 = __uint_as_float(wreg[j].w);
                u16* dst = W2g + oc * WST;
                if (yx0 >= 0     && yx0 < 81)     dst[yx0]     = f2bf(f0);
                if (yx0 + 1 >= 0 && yx0 + 1 < 81) dst[yx0 + 1] = f2bf(f1);
                if (yx0 + 2 >= 0 && yx0 + 2 < 81) dst[yx0 + 2] = f2bf(f2);
                if (yx0 + 3 < 81)                 dst[yx0 + 3] = f2bf(f3);
                oc += 11; ch += 14; if (ch >= 22) { ch -= 22; oc += 1; }
            }
        }

        // issue prefetch for group g+1 (hides under MFMA(g) + conv1(g+1))
        if (g < 63) {
            const int base4 = ((g + 1) * 81) & ~3;
            int oc = oc_s, ch = ch_s;
            #pragma unroll
            for (int j = 0; j < NCHUNK; ++j) {
                int off = base4 + ch * 4;
                off = off > 5180 ? 5180 : off;
                wreg[j] = *(const uint4*)(W2 + (size_t)oc * 5184 + off);
                oc += 11; ch += 14; if (ch >= 22) { ch -= 22; oc += 1; }
            }
        }

        __syncthreads();   // Hl(g), W2g(g) ready

        // ---- conv2 partial: 3 MFMA K-steps (K=96 incl. zero pad) ----
        #pragma unroll
        for (int s = 0; s < 3; ++s) {
            const int ko = s * 32 + g4 * 8;
            bf16x8 a0  = *(const bf16x8*)(Hl + (n16     ) * HST + ko);
            bf16x8 a1  = *(const bf16x8*)(Hl + (16 + n16) * HST + ko);
            bf16x8 vb0 = *(const bf16x8*)(W2g + (w * 32 + n16     ) * WST + ko);
            bf16x8 vb1 = *(const bf16x8*)(W2g + (w * 32 + 16 + n16) * WST + ko);
            acc[0][0] = __builtin_amdgcn_mfma_f32_16x16x32_bf16(a0, vb0, acc[0][0], 0, 0, 0);
            acc[0][1] = __builtin_amdgcn_mfma_f32_16x16x32_bf16(a0, vb1, acc[0][1], 0, 0, 0);
            acc[1][0] = __builtin_amdgcn_mfma_f32_16x16x32_bf16(a1, vb0, acc[1][0], 0, 0, 0);
            acc[1][1] = __builtin_amdgcn_mfma_f32_16x16x32_bf16(a1, vb1, acc[1][1], 0, 0, 0);
        }
    }

    // ---- epilogue: + b2, write fp32 (B,N,128), guard tail rows ----
    const float bias0 = b2[w * 32 + n16];
    const float bias1 = b2[w * 32 + 16 + n16];
    #pragma unroll
    for (int mt = 0; mt < 2; ++mt) {
        #pragma unroll
        for (int r = 0; r < 4; ++r) {
            int p = mt * 16 + g4 * 4 + r;
            int gp = blk * PP + p;
            if (p < PP && gp < NPATCH) {
                size_t rowo = (size_t)gp * 128;
                out[rowo + w * 32 + n16]      = acc[mt][0][r] + bias0;
                out[rowo + w * 32 + 16 + n16] = acc[mt][1][r] + bias1;
            }
        }
    }
}

extern "C" void kernel_launch(void* const* d_in, const int* in_sizes, int n_in,
                              void* d_out, int out_size, void* d_ws, size_t ws_size,
                              hipStream_t stream)
{
    const float* images = (const float*)d_in[0];
    const float* coords = (const float*)d_in[1];
    const int*   t_src  = (const int*)d_in[2];
    const float* W1     = (const float*)d_in[3];
    const float* b1     = (const float*)d_in[4];
    const float* W2     = (const float*)d_in[5];
    const float* b2     = (const float*)d_in[6];
    float* out = (float*)d_out;

    const int grid = (NPATCH + PP - 1) / PP;   // 1171
    hipLaunchKernelGGL(patch_embed, dim3(grid), dim3(NTHR), 0, stream,
                       images, coords, t_src, W1, b1, W2, b2, out);
}

// Round 11
// 341.188 us; speedup vs baseline: 4.0276x; 4.0276x over previous
//
#include <hip/hip_runtime.h>
#include <stdint.h>

#define NTHR 256
#define PP   28              // patches per block (252 conv1 tasks <= 256 threads)
#define HST  104             // H row stride in bf16 elems (52 dw == 20 mod 32)
#define WST  104             // W2g row stride in bf16 elems
#define NPATCH 32768
#define W2B_ELEMS (64*128*WST)   // 851,968 u16 = 1,703,936 B in d_ws
#define HW (384*384)

typedef __attribute__((ext_vector_type(8))) short bf16x8;
typedef __attribute__((ext_vector_type(4))) float f32x4;
typedef uint32_t u32;
typedef uint16_t u16;

__device__ __forceinline__ u16 f2bf(float f){
    u32 x = __float_as_uint(f);
    return (u16)((x + 0x7fffu + ((x >> 16) & 1u)) >> 16);
}
__device__ __forceinline__ u32 pack2(float a, float b){
    return (u32)f2bf(a) | ((u32)f2bf(b) << 16);
}

// ---- prep: W2 fp32 [128][64][81] -> bf16 d_ws [64 g][128 oc][104], zeros in [81,104) ----
__global__ void w2_prep(const float* __restrict__ W2, u16* __restrict__ W2b){
    int i = blockIdx.x * 256 + threadIdx.x;
    if (i >= W2B_ELEMS) return;
    int g   = i / (128 * WST);
    int rem = i - g * (128 * WST);
    int oc  = rem / WST;
    int k   = rem - oc * WST;
    u16 v = 0;
    if (k < 81) v = f2bf(W2[(size_t)oc * 5184 + g * 81 + k]);
    W2b[i] = v;
}

template<bool USEWS>
__global__ __launch_bounds__(NTHR, 2)
void patch_embed(const float* __restrict__ images,
                 const float* __restrict__ coords,
                 const int*   __restrict__ t_src,
                 const float* __restrict__ W1,
                 const float* __restrict__ b1,
                 const float* __restrict__ W2,
                 const u16*   __restrict__ W2b,
                 const float* __restrict__ b2,
                 float* __restrict__ out)
{
    __shared__ __align__(16) u16 Hl[32 * HST];       //  6656 B (rows 28..31, k>=81 stay zero)
    __shared__ __align__(16) u16 W2g[128 * WST];     // 26624 B (fully rewritten per group)
    __shared__ int poff[PP];                         // total ~33.4 KB

    const int tid  = threadIdx.x;
    const int blk  = blockIdx.x;
    const int lane = tid & 63;
    const int w    = tid >> 6;
    const int n16  = lane & 15;
    const int g4   = lane >> 4;

    // per-patch source offsets (round-half-even like jnp.round)
    if (tid < PP) {
        int gp = blk * PP + tid;
        if (gp >= NPATCH) gp = NPATCH - 1;           // tail block: valid dummy
        int b = gp >> 11;
        int n = gp & 2047;
        float cx = coords[(size_t)(b * 2048 + n) * 2 + 0];
        float cy = coords[(size_t)(b * 2048 + n) * 2 + 1];
        int u = (int)rintf(cx * 384.0f);
        int v = (int)rintf(cy * 384.0f);
        u = min(max(u, 4), 379);
        v = min(max(v, 4), 379);
        int t = t_src[b * 2048 + n];
        t = min(max(t, 0), 15);
        poff[tid] = ((b * 16 + t) * 3) * HW + (v - 4) * 384 + (u - 4);
    }
    // zero Hl once (rows 28..31 and k in [81,104) stay zero forever)
    {
        u32* Hw = (u32*)Hl;
        for (int j = tid; j < 32 * (HST / 2); j += NTHR) Hw[j] = 0u;
    }
    __syncthreads();

    // fixed conv1 task: (p0, y0). Load 3 rows x 27 floats DIRECTLY global -> registers.
    const bool has = tid < PP * 9;                    // 252 tasks
    const int p0 = has ? tid / 9 : 0;
    const int y0 = has ? tid - 9 * (tid / 9) : 0;
    float rf[3][27];
    {
        const int base = poff[p0];
        #pragma unroll
        for (int dy = 0; dy < 3; ++dy) {
            const int yy = y0 - 1 + dy;               // real image row within patch
            const bool vrow = has && (yy >= 0) && (yy <= 8);
            #pragma unroll
            for (int c = 0; c < 3; ++c) {
                #pragma unroll
                for (int x = 0; x < 9; ++x) rf[dy][c * 9 + x] = 0.f;
            }
            if (vrow) {
                #pragma unroll
                for (int c = 0; c < 3; ++c) {
                    const float* rp = images + (size_t)base + c * HW + yy * 384;
                    #pragma unroll
                    for (int x = 0; x < 9; ++x) rf[dy][c * 9 + x] = rp[x];
                }
            }
        }
    }

    f32x4 acc[2][2];
    #pragma unroll
    for (int mt = 0; mt < 2; ++mt)
        #pragma unroll
        for (int nt = 0; nt < 2; ++nt) acc[mt][nt] = (f32x4){0.f, 0.f, 0.f, 0.f};

    #pragma unroll 1
    for (int g = 0; g < 64; ++g) {
        // ---- conv1 for channel g: pure register FMAs ----
        const float* W1c = W1 + (size_t)g * 27;
        const float bias = b1[g];
        u16 h9[9];
        {
            float a[9];
            #pragma unroll
            for (int x = 0; x < 9; ++x) a[x] = bias;
            #pragma unroll
            for (int dy = 0; dy < 3; ++dy) {
                #pragma unroll
                for (int c = 0; c < 3; ++c) {
                    const float* rr = rf[dy] + c * 9;
                    const int wi = c * 9 + dy * 3;
                    const float w0 = W1c[wi], w1 = W1c[wi + 1], w2 = W1c[wi + 2];
                    #pragma unroll
                    for (int xo = 0; xo < 9; ++xo) {
                        a[xo] = fmaf(rr[xo], w1, a[xo]);
                        if (xo >= 1) a[xo] = fmaf(rr[xo - 1], w0, a[xo]);
                        if (xo <= 7) a[xo] = fmaf(rr[xo + 1], w2, a[xo]);
                    }
                }
            }
            #pragma unroll
            for (int xo = 0; xo < 9; ++xo) {
                float v = a[xo] > 0.f ? a[xo] : 0.f;   // ReLU
                h9[xo] = f2bf(v);
            }
        }

        __syncthreads();   // all waves done with MFMA(g-1) reads of Hl/W2g

        // H stores (k = y0*9+xo in [0,81))
        if (has) {
            #pragma unroll
            for (int xo = 0; xo < 9; ++xo) Hl[p0 * HST + y0 * 9 + xo] = h9[xo];
        }

        // W2g(g) staging
        if constexpr (USEWS) {
            // plain copy: prepped bf16, identical padded layout -> linear b128 writes
            const uint4* src = (const uint4*)(W2b + (size_t)g * (128 * WST));
            uint4* dst = (uint4*)W2g;
            #pragma unroll
            for (int i = 0; i < 7; ++i) {             // 1664 chunks = 6*256 + 128
                int c = tid + i * 256;
                if (i < 6 || tid < 128) dst[c] = src[c];
            }
        } else {
            // fallback: inline fp32->bf16 conversion from W2
            for (int i = tid; i < 128 * (WST / 2); i += NTHR) {
                int oc = i / (WST / 2);
                int pr = i - oc * (WST / 2);
                int k0 = pr * 2;
                const float* so = W2 + (size_t)oc * 5184 + g * 81;
                float v0 = 0.f, v1 = 0.f;
                if (k0 < 81) v0 = so[k0];
                if (k0 < 80) v1 = so[k0 + 1];
                ((u32*)W2g)[i] = pack2(v0, v1);
            }
        }

        __syncthreads();   // Hl(g), W2g(g) ready

        // ---- conv2 partial: 3 MFMA K-steps (K = 96 incl. zero pad) ----
        #pragma unroll
        for (int s = 0; s < 3; ++s) {
            const int ko = s * 32 + g4 * 8;
            bf16x8 a0  = *(const bf16x8*)(Hl + (n16     ) * HST + ko);
            bf16x8 a1  = *(const bf16x8*)(Hl + (16 + n16) * HST + ko);
            bf16x8 vb0 = *(const bf16x8*)(W2g + (w * 32 + n16     ) * WST + ko);
            bf16x8 vb1 = *(const bf16x8*)(W2g + (w * 32 + 16 + n16) * WST + ko);
            acc[0][0] = __builtin_amdgcn_mfma_f32_16x16x32_bf16(a0, vb0, acc[0][0], 0, 0, 0);
            acc[0][1] = __builtin_amdgcn_mfma_f32_16x16x32_bf16(a0, vb1, acc[0][1], 0, 0, 0);
            acc[1][0] = __builtin_amdgcn_mfma_f32_16x16x32_bf16(a1, vb0, acc[1][0], 0, 0, 0);
            acc[1][1] = __builtin_amdgcn_mfma_f32_16x16x32_bf16(a1, vb1, acc[1][1], 0, 0, 0);
        }
    }

    // ---- epilogue: + b2, write fp32 (B,N,128), guard tail rows ----
    const float bias0 = b2[w * 32 + n16];
    const float bias1 = b2[w * 32 + 16 + n16];
    #pragma unroll
    for (int mt = 0; mt < 2; ++mt) {
        #pragma unroll
        for (int r = 0; r < 4; ++r) {
            int p = mt * 16 + g4 * 4 + r;
            int gp = blk * PP + p;
            if (p < PP && gp < NPATCH) {
                size_t rowo = (size_t)gp * 128;
                out[rowo + w * 32 + n16]      = acc[mt][0][r] + bias0;
                out[rowo + w * 32 + 16 + n16] = acc[mt][1][r] + bias1;
            }
        }
    }
}

extern "C" void kernel_launch(void* const* d_in, const int* in_sizes, int n_in,
                              void* d_out, int out_size, void* d_ws, size_t ws_size,
                              hipStream_t stream)
{
    const float* images = (const float*)d_in[0];
    const float* coords = (const float*)d_in[1];
    const int*   t_src  = (const int*)d_in[2];
    const float* W1     = (const float*)d_in[3];
    const float* b1     = (const float*)d_in[4];
    const float* W2     = (const float*)d_in[5];
    const float* b2     = (const float*)d_in[6];
    float* out = (float*)d_out;
    u16* W2b = (u16*)d_ws;

    const int grid = (NPATCH + PP - 1) / PP;   // 1171
    const bool usews = ws_size >= (size_t)W2B_ELEMS * sizeof(u16);   // 1.70 MB

    if (usews) {
        hipLaunchKernelGGL(w2_prep, dim3((W2B_ELEMS + 255) / 256), dim3(256), 0, stream,
                           W2, W2b);
        hipLaunchKernelGGL(patch_embed<true>, dim3(grid), dim3(NTHR), 0, stream,
                           images, coords, t_src, W1, b1, W2, W2b, b2, out);
    } else {
        hipLaunchKernelGGL(patch_embed<false>, dim3(grid), dim3(NTHR), 0, stream,
                           images, coords, t_src, W1, b1, W2, W2b, b2, out);
    }
}

// Round 12
// 241.334 us; speedup vs baseline: 5.6941x; 1.4138x over previous
//
#include <hip/hip_runtime.h>
#include <stdint.h>

#define NTHR 256
#define PP   28              // patches per block (252 conv1 tasks <= 256 threads)
#define HST  104             // H row stride in bf16 elems
#define WST  104             // W2b row stride in bf16 elems
#define NPATCH 32768
#define W2B_ELEMS (64*128*WST)   // 851,968 u16 = 1,703,936 B in d_ws
#define HW (384*384)

typedef __attribute__((ext_vector_type(8))) short bf16x8;
typedef __attribute__((ext_vector_type(4))) float f32x4;
typedef uint32_t u32;
typedef uint16_t u16;

__device__ __forceinline__ u16 f2bf(float f){
    u32 x = __float_as_uint(f);
    return (u16)((x + 0x7fffu + ((x >> 16) & 1u)) >> 16);
}
__device__ __forceinline__ u32 pack2(float a, float b){
    return (u32)f2bf(a) | ((u32)f2bf(b) << 16);
}
__device__ __forceinline__ bf16x8 u4bf(uint4 x){
    union { uint4 u; bf16x8 b; } c; c.u = x; return c.b;
}

// ---- prep: W2 fp32 [128][64][81] -> bf16 d_ws [64 g][128 oc][104], zeros in [81,104) ----
__global__ void w2_prep(const float* __restrict__ W2, u16* __restrict__ W2b){
    int i = blockIdx.x * 256 + threadIdx.x;
    if (i >= W2B_ELEMS) return;
    int g   = i / (128 * WST);
    int rem = i - g * (128 * WST);
    int oc  = rem / WST;
    int k   = rem - oc * WST;
    u16 v = 0;
    if (k < 81) v = f2bf(W2[(size_t)oc * 5184 + g * 81 + k]);
    W2b[i] = v;
}

// load B fragments for group g into registers (bypasses LDS entirely)
template<bool USEWS>
__device__ __forceinline__ void load_B(const u16* __restrict__ W2b,
                                       const float* __restrict__ W2,
                                       int g, int oc0, int oc1, int g4,
                                       uint4 PB[3][2])
{
    if constexpr (USEWS) {
        const u16* base = W2b + (size_t)g * (128 * WST);
        #pragma unroll
        for (int s = 0; s < 3; ++s) {
            const int ko = s * 32 + g4 * 8;
            PB[s][0] = *(const uint4*)(base + oc0 * WST + ko);
            PB[s][1] = *(const uint4*)(base + oc1 * WST + ko);
        }
    } else {
        #pragma unroll
        for (int s = 0; s < 3; ++s) {
            const int ko = s * 32 + g4 * 8;
            #pragma unroll
            for (int half = 0; half < 2; ++half) {
                const float* so = W2 + (size_t)(half ? oc1 : oc0) * 5184 + g * 81;
                u32 q0 = pack2(ko     < 81 ? so[ko]     : 0.f, ko + 1 < 81 ? so[ko + 1] : 0.f);
                u32 q1 = pack2(ko + 2 < 81 ? so[ko + 2] : 0.f, ko + 3 < 81 ? so[ko + 3] : 0.f);
                u32 q2 = pack2(ko + 4 < 81 ? so[ko + 4] : 0.f, ko + 5 < 81 ? so[ko + 5] : 0.f);
                u32 q3 = pack2(ko + 6 < 81 ? so[ko + 6] : 0.f, ko + 7 < 81 ? so[ko + 7] : 0.f);
                PB[s][half] = (uint4){q0, q1, q2, q3};
            }
        }
    }
}

template<bool USEWS>
__global__ __launch_bounds__(NTHR)
void patch_embed(const float* __restrict__ images,
                 const float* __restrict__ coords,
                 const int*   __restrict__ t_src,
                 const float* __restrict__ W1,
                 const float* __restrict__ b1,
                 const float* __restrict__ W2,
                 const u16*   __restrict__ W2b,
                 const float* __restrict__ b2,
                 float* __restrict__ out)
{
    __shared__ __align__(16) u16 Hl[2][32 * HST];    // 13312 B double-buffered H
    __shared__ int poff[PP];                         // total ~13.4 KB LDS

    const int tid  = threadIdx.x;
    const int blk  = blockIdx.x;
    const int lane = tid & 63;
    const int w    = tid >> 6;
    const int n16  = lane & 15;
    const int g4   = lane >> 4;

    // per-patch source offsets (round-half-even like jnp.round)
    if (tid < PP) {
        int gp = blk * PP + tid;
        if (gp >= NPATCH) gp = NPATCH - 1;           // tail block: valid dummy
        int b = gp >> 11;
        int n = gp & 2047;
        float cx = coords[(size_t)(b * 2048 + n) * 2 + 0];
        float cy = coords[(size_t)(b * 2048 + n) * 2 + 1];
        int u = (int)rintf(cx * 384.0f);
        int v = (int)rintf(cy * 384.0f);
        u = min(max(u, 4), 379);
        v = min(max(v, 4), 379);
        int t = t_src[b * 2048 + n];
        t = min(max(t, 0), 15);
        poff[tid] = ((b * 16 + t) * 3) * HW + (v - 4) * 384 + (u - 4);
    }
    // zero both H buffers once (rows 28..31 and k in [81,104) stay zero forever)
    {
        u32* Hz = (u32*)Hl;
        #pragma unroll
        for (int j = 0; j < 13; ++j) Hz[tid + j * NTHR] = 0u;   // 2*32*52 = 3328 u32
    }
    __syncthreads();

    // fixed conv1 task: (p0, y0). Load 3 rows x 27 floats DIRECTLY global -> registers.
    const bool has = tid < PP * 9;                    // 252 tasks
    const int p0 = has ? tid / 9 : 0;
    const int y0 = has ? tid - 9 * (tid / 9) : 0;
    float rf[3][27];
    {
        const int base = poff[p0];
        #pragma unroll
        for (int dy = 0; dy < 3; ++dy) {
            const int yy = y0 - 1 + dy;               // real image row within patch
            const bool vrow = has && (yy >= 0) && (yy <= 8);
            #pragma unroll
            for (int j = 0; j < 27; ++j) rf[dy][j] = 0.f;
            if (vrow) {
                #pragma unroll
                for (int c = 0; c < 3; ++c) {
                    const float* rp = images + (size_t)base + c * HW + yy * 384;
                    #pragma unroll
                    for (int x = 0; x < 9; ++x) rf[dy][c * 9 + x] = rp[x];
                }
            }
        }
    }

    // B-fragment register prefetch for g=0
    const int oc0 = w * 32 + n16;
    const int oc1 = oc0 + 16;
    uint4 PB[3][2];
    load_B<USEWS>(W2b, W2, 0, oc0, oc1, g4, PB);

    f32x4 acc[2][2];
    #pragma unroll
    for (int mt = 0; mt < 2; ++mt)
        #pragma unroll
        for (int nt = 0; nt < 2; ++nt) acc[mt][nt] = (f32x4){0.f, 0.f, 0.f, 0.f};

    #pragma unroll 1
    for (int g = 0; g < 64; ++g) {
        // ---- conv1 for channel g: pure register FMAs ----
        const float* W1c = W1 + (size_t)g * 27;
        const float bias = b1[g];
        u16 h9[9];
        {
            float a[9];
            #pragma unroll
            for (int x = 0; x < 9; ++x) a[x] = bias;
            #pragma unroll
            for (int dy = 0; dy < 3; ++dy) {
                #pragma unroll
                for (int c = 0; c < 3; ++c) {
                    const float* rr = rf[dy] + c * 9;
                    const int wi = c * 9 + dy * 3;
                    const float w0 = W1c[wi], w1 = W1c[wi + 1], w2 = W1c[wi + 2];
                    #pragma unroll
                    for (int xo = 0; xo < 9; ++xo) {
                        a[xo] = fmaf(rr[xo], w1, a[xo]);
                        if (xo >= 1) a[xo] = fmaf(rr[xo - 1], w0, a[xo]);
                        if (xo <= 7) a[xo] = fmaf(rr[xo + 1], w2, a[xo]);
                    }
                }
            }
            #pragma unroll
            for (int xo = 0; xo < 9; ++xo) {
                float v = a[xo] > 0.f ? a[xo] : 0.f;   // ReLU
                h9[xo] = f2bf(v);
            }
        }

        // H stores into buffer g&1 (k = y0*9+xo in [0,81))
        {
            u16* Hb = &Hl[g & 1][0];
            if (has) {
                #pragma unroll
                for (int xo = 0; xo < 9; ++xo) Hb[p0 * HST + y0 * 9 + xo] = h9[xo];
            }
        }

        __syncthreads();   // Hl(g) visible; MFMA(g-1) reads of buf[(g-1)&1] all done

        // ---- conv2 partial: 3 MFMA K-steps, A from LDS buf, B from registers ----
        {
            const u16* Hb = &Hl[g & 1][0];
            #pragma unroll
            for (int s = 0; s < 3; ++s) {
                const int ko = s * 32 + g4 * 8;
                bf16x8 a0  = *(const bf16x8*)(Hb + (n16     ) * HST + ko);
                bf16x8 a1  = *(const bf16x8*)(Hb + (16 + n16) * HST + ko);
                bf16x8 vb0 = u4bf(PB[s][0]);
                bf16x8 vb1 = u4bf(PB[s][1]);
                acc[0][0] = __builtin_amdgcn_mfma_f32_16x16x32_bf16(a0, vb0, acc[0][0], 0, 0, 0);
                acc[0][1] = __builtin_amdgcn_mfma_f32_16x16x32_bf16(a0, vb1, acc[0][1], 0, 0, 0);
                acc[1][0] = __builtin_amdgcn_mfma_f32_16x16x32_bf16(a1, vb0, acc[1][0], 0, 0, 0);
                acc[1][1] = __builtin_amdgcn_mfma_f32_16x16x32_bf16(a1, vb1, acc[1][1], 0, 0, 0);
            }
        }

        // reload PB for g+1 (WAR-safe after MFMA issue; latency hides under conv1(g+1))
        if (g < 63) load_B<USEWS>(W2b, W2, g + 1, oc0, oc1, g4, PB);
    }

    // ---- epilogue: + b2, write fp32 (B,N,128), guard tail rows ----
    const float bias0 = b2[oc0];
    const float bias1 = b2[oc1];
    #pragma unroll
    for (int mt = 0; mt < 2; ++mt) {
        #pragma unroll
        for (int r = 0; r < 4; ++r) {
            int p = mt * 16 + g4 * 4 + r;
            int gp = blk * PP + p;
            if (p < PP && gp < NPATCH) {
                size_t rowo = (size_t)gp * 128;
                out[rowo + oc0] = acc[mt][0][r] + bias0;
                out[rowo + oc1] = acc[mt][1][r] + bias1;
            }
        }
    }
}

extern "C" void kernel_launch(void* const* d_in, const int* in_sizes, int n_in,
                              void* d_out, int out_size, void* d_ws, size_t ws_size,
                              hipStream_t stream)
{
    const float* images = (const float*)d_in[0];
    const float* coords = (const float*)d_in[1];
    const int*   t_src  = (const int*)d_in[2];
    const float* W1     = (const float*)d_in[3];
    const float* b1     = (const float*)d_in[4];
    const float* W2     = (const float*)d_in[5];
    const float* b2     = (const float*)d_in[6];
    float* out = (float*)d_out;
    u16* W2b = (u16*)d_ws;

    const int grid = (NPATCH + PP - 1) / PP;   // 1171
    const bool usews = ws_size >= (size_t)W2B_ELEMS * sizeof(u16);   // 1.70 MB

    if (usews) {
        hipLaunchKernelGGL(w2_prep, dim3((W2B_ELEMS + 255) / 256), dim3(256), 0, stream,
                           W2, W2b);
        hipLaunchKernelGGL(patch_embed<true>, dim3(grid), dim3(NTHR), 0, stream,
                           images, coords, t_src, W1, b1, W2, W2b, b2, out);
    } else {
        hipLaunchKernelGGL(patch_embed<false>, dim3(grid), dim3(NTHR), 0, stream,
                           images, coords, t_src, W1, b1, W2, W2b, b2, out);
    }
}